// Round 3
// baseline (2207.781 us; speedup 1.0000x reference)
//
#include <hip/hip_runtime.h>

// Upsampling 2x NN: (16,64,256,256) fp32 -> (16,64,512,512) fp32.
// ===== DIAGNOSTIC ROUND (one-off ablation; output still exactly correct) =====
// Finding so far: harness dur_us includes a ~685us 4GiB poison-fill each
// iteration (fill @ 6.27 TB/s). Kernel-attributable: v1~489us, v2~526, v3~611
// (~2.2-2.7 TB/s) vs ~215us roofline. Our kernel never appears in rocprof
// top-5 (always < the 685us fills), so we have NO counters for it.
// This round: two long dispatches that WILL surface in top-5 with counters:
//   A) diag_write6: pure dense f4 writes, 6 passes over output (6 GiB).
//      -> isolates the store path in our persistent-grid structure.
//   B) diag_full2: real upsample (v2 minus nt), 2 passes; 2nd pass leaves
//      correct output. -> FETCH/WRITE reveal RFO/eviction amplification.

using f2v = __attribute__((ext_vector_type(2))) float;
using f4v = __attribute__((ext_vector_type(4))) float;

constexpr int BLOCK = 256;
constexpr int GRID  = 2048;                               // 8 blocks/CU
constexpr long long NTHREADS = (long long)BLOCK * GRID;   // 524,288

constexpr long long N_OUT_F4 = 1LL << 26;   // 67,108,864 float4 = 1 GiB output
constexpr long long N_IN_F2  = 1LL << 25;   // 33,554,432 float2 = 256 MiB input
constexpr int IN_V2_PER_ROW  = 128;
constexpr int OUT_V4_PER_ROW = 128;
constexpr int ITERS  = (int)(N_IN_F2 / NTHREADS);         // 64
constexpr int UNROLL = 8;
constexpr long long OUT_STEP =
    (NTHREADS / IN_V2_PER_ROW) * 2LL * OUT_V4_PER_ROW;    // 1,048,576 f4

static_assert(N_IN_F2 % NTHREADS == 0, "no tail");
static_assert(ITERS % UNROLL == 0, "clean unroll");

// A) Pure-write probe: dense, fill-like, 6 full passes (6 GiB of stores).
__global__ __launch_bounds__(BLOCK)
void diag_write6(f4v* __restrict__ out) {
    const long long t0 = (long long)blockIdx.x * BLOCK + threadIdx.x;
    const f4v val = {1.f, 2.f, 3.f, 4.f};
    #pragma unroll 1
    for (int pass = 0; pass < 6; ++pass) {
        for (long long i = t0; i < N_OUT_F4; i += NTHREADS)
            out[i] = val;
        asm volatile("" ::: "memory");  // keep passes distinct
    }
}

// B) Real upsample, 2 passes (idempotent; final pass leaves exact output).
//    v2 structure with nt hints removed (best persistent variant so far).
__global__ __launch_bounds__(BLOCK)
void diag_full2(const f2v* __restrict__ in, f4v* __restrict__ out) {
    const long long t0 = (long long)blockIdx.x * BLOCK + threadIdx.x;
    const int col      = (int)(t0 & (IN_V2_PER_ROW - 1));
    const long long r  = t0 >> 7;

    #pragma unroll 1
    for (int pass = 0; pass < 2; ++pass) {
        const f2v* ip = in + t0;
        f4v* op = out + r * (2 * OUT_V4_PER_ROW) + col;
        for (int k = 0; k < ITERS; k += UNROLL) {
            f2v v[UNROLL];
            #pragma unroll
            for (int u = 0; u < UNROLL; ++u)
                v[u] = ip[(long long)u * NTHREADS];
            #pragma unroll
            for (int u = 0; u < UNROLL; ++u) {
                f4v o = {v[u].x, v[u].x, v[u].y, v[u].y};
                f4v* p = op + (long long)u * OUT_STEP;
                p[0]              = o;   // output row 2r
                p[OUT_V4_PER_ROW] = o;   // output row 2r+1
            }
            ip += (long long)UNROLL * NTHREADS;
            op += (long long)UNROLL * OUT_STEP;
        }
        asm volatile("" ::: "memory");
    }
}

extern "C" void kernel_launch(void* const* d_in, const int* in_sizes, int n_in,
                              void* d_out, int out_size, void* d_ws, size_t ws_size,
                              hipStream_t stream) {
    const f2v* in = (const f2v*)d_in[0];
    f4v* out = (f4v*)d_out;
    // Diagnostics first; correctness-bearing kernel last.
    diag_write6<<<dim3(GRID), dim3(BLOCK), 0, stream>>>(out);
    diag_full2<<<dim3(GRID), dim3(BLOCK), 0, stream>>>(in, out);
}